// Round 8
// baseline (703.909 us; speedup 1.0000x reference)
//
#include <hip/hip_runtime.h>
#include <hip/hip_bf16.h>
#include <math.h>

#define B_   4
#define T_   2048
#define V_   512
#define D_   256
#define H_   4
#define DH_  64
#define NB_  32
#define DFF_ 1024
#define NL_  2

typedef __attribute__((ext_vector_type(8))) short short8_t;
typedef __attribute__((ext_vector_type(4))) float float4_t;

#define MFMA16(a,b,c) __builtin_amdgcn_mfma_f32_16x16x32_bf16(a,b,c,0,0,0)

__device__ __forceinline__ unsigned short f2bf_bits(float f) {
    unsigned u = __float_as_uint(f);
    u += 0x7fffu + ((u >> 16) & 1u);
    return (unsigned short)(u >> 16);
}

// ---------------------------------------------------------------------------
// Weight transpose+cast: W[K][N] fp32 -> Wt[N][K] bf16. One 32x32 tile/block.
// Wq/Wk land in a fused wqkt buffer: [layer][512][256] (Q rows 0-255, K 256-511)
// ---------------------------------------------------------------------------
__global__ __launch_bounds__(256) void wt_kernel(
    const float* __restrict__ Wq, const float* __restrict__ Wk,
    const float* __restrict__ Wv, const float* __restrict__ Wo,
    const float* __restrict__ W1, const float* __restrict__ W2,
    const float* __restrict__ Wout,
    unsigned short* __restrict__ wqkt,
    unsigned short* __restrict__ wvt, unsigned short* __restrict__ wot,
    unsigned short* __restrict__ w1t, unsigned short* __restrict__ w2t,
    unsigned short* __restrict__ woutt)
{
    __shared__ float tile[32][33];
    int bx = blockIdx.x, tid = threadIdx.x;
    const float* src; unsigned short* dst; int Kd, Nd, tr, tc;
    if (bx < 512) {                    // Wq/Wk/Wv/Wo, 2 layers each, 256x256
        int am = bx >> 6, t = bx & 63;
        int m4 = am >> 1, layer = am & 1;
        const float* s4[4] = {Wq, Wk, Wv, Wo};
        src = s4[m4] + (long)layer * 65536;
        if (m4 == 0)      dst = wqkt + (long)layer * 131072;
        else if (m4 == 1) dst = wqkt + (long)layer * 131072 + 65536;
        else if (m4 == 2) dst = wvt + (long)layer * 65536;
        else              dst = wot + (long)layer * 65536;
        Kd = 256; Nd = 256; tr = t >> 3; tc = t & 7;
    } else if (bx < 1024) {            // W1: 2 x (256x1024)
        int idx = bx - 512, mat = idx >> 8, t = idx & 255;
        src = W1 + (long)mat * 262144; dst = w1t + (long)mat * 262144;
        Kd = 256; Nd = 1024; tr = t >> 5; tc = t & 31;
    } else if (bx < 1536) {            // W2: 2 x (1024x256)
        int idx = bx - 1024, mat = idx >> 8, t = idx & 255;
        src = W2 + (long)mat * 262144; dst = w2t + (long)mat * 262144;
        Kd = 1024; Nd = 256; tr = t >> 3; tc = t & 7;
    } else {                           // Wout: 256x512
        int t = bx - 1536;
        src = Wout; dst = woutt; Kd = 256; Nd = 512; tr = t >> 4; tc = t & 15;
    }
    int kr = tid >> 3, nc4 = (tid & 7) * 4;
    float4_t v = *(const float4_t*)&src[(long)(tr * 32 + kr) * Nd + tc * 32 + nc4];
    for (int j = 0; j < 4; ++j) tile[kr][nc4 + j] = v[j];
    __syncthreads();
    int nr = tid >> 3, kc4 = (tid & 7) * 4;
    unsigned short tmp[4];
    for (int j = 0; j < 4; ++j) tmp[j] = f2bf_bits(tile[kc4 + j][nr]);
    uint2 uu;
    uu.x = (unsigned)tmp[0] | ((unsigned)tmp[1] << 16);
    uu.y = (unsigned)tmp[2] | ((unsigned)tmp[3] << 16);
    *(uint2*)&dst[(long)(tc * 32 + nr) * Kd + tr * 32 + kc4] = uu;
}

// ---------------------------------------------------------------------------
// Token embedding gather + rank-2 delta projection
// ---------------------------------------------------------------------------
__global__ __launch_bounds__(256) void embed_kernel(
    const int* __restrict__ tokens, const float* __restrict__ emb,
    const float* __restrict__ w_in, const float* __restrict__ w_out,
    float* __restrict__ x, float* __restrict__ delta)
{
    int bt = blockIdx.x;
    int d  = threadIdx.x;
    int tok = tokens[bt];
    float e = emb[tok * D_ + d];
    x[(long)bt * D_ + d] = e;

    __shared__ float r0s[256], r1s[256];
    r0s[d] = e * w_in[d * 2 + 0];
    r1s[d] = e * w_in[d * 2 + 1];
    __syncthreads();
    for (int off = 128; off > 0; off >>= 1) {
        if (d < off) { r0s[d] += r0s[d + off]; r1s[d] += r1s[d + off]; }
        __syncthreads();
    }
    float r0 = r0s[0], r1 = r1s[0];
    if (d < H_ * NB_) {
        delta[(long)bt * (H_ * NB_) + d] =
            r0 * w_out[d] + r1 * w_out[H_ * NB_ + d];
    }
}

// ---------------------------------------------------------------------------
// cumsum over T per (b, channel) + cos/sin
// ---------------------------------------------------------------------------
__global__ __launch_bounds__(256) void cumsum_kernel(
    const float* __restrict__ delta, const float* __restrict__ omega,
    float* __restrict__ cosb, float* __restrict__ sinb)
{
    int c = blockIdx.x & (H_ * NB_ - 1);
    int b = blockIdx.x >> 7;
    int tid = threadIdx.x;
    float om = omega[c];
    int h = c >> 5, nb = c & (NB_ - 1);

    float vals[8];
    float s = 0.0f;
    for (int i = 0; i < 8; ++i) {
        int t = tid * 8 + i;
        vals[i] = delta[((long)b * T_ + t) * (H_ * NB_) + c];
        s += vals[i];
    }
    __shared__ float sc[256];
    sc[tid] = s;
    __syncthreads();
    for (int off = 1; off < 256; off <<= 1) {
        float v = (tid >= off) ? sc[tid - off] : 0.0f;
        __syncthreads();
        sc[tid] += v;
        __syncthreads();
    }
    float run = sc[tid] - s;
    for (int i = 0; i < 8; ++i) {
        run += vals[i];
        float ang = run * om;
        int t = tid * 8 + i;
        long oi = ((long)(b * H_ + h) * T_ + t) * NB_ + nb;
        cosb[oi] = cosf(ang);
        sinb[oi] = sinf(ang);
    }
}

// ---------------------------------------------------------------------------
// LayerNorm (fp32 in) -> bf16 out. Wave-per-row, no LDS, no barriers.
// ---------------------------------------------------------------------------
__global__ __launch_bounds__(256) void ln_kernel(
    const float* __restrict__ x, const float* __restrict__ g,
    const float* __restrict__ b, unsigned short* __restrict__ out)
{
    int w = threadIdx.x >> 6, lane = threadIdx.x & 63;
    long row = (long)blockIdx.x * 4 + w;
    float4_t v = *(const float4_t*)&x[row * D_ + lane * 4];
    float s = v[0] + v[1] + v[2] + v[3];
    float q = v[0]*v[0] + v[1]*v[1] + v[2]*v[2] + v[3]*v[3];
    for (int off = 1; off < 64; off <<= 1) {
        s += __shfl_xor(s, off);
        q += __shfl_xor(q, off);
    }
    float mu  = s * (1.0f / D_);
    float var = q * (1.0f / D_) - mu * mu;
    float inv = rsqrtf(var + 1e-5f);
    float4_t gg = *(const float4_t*)&g[lane * 4];
    float4_t bb = *(const float4_t*)&b[lane * 4];
    unsigned short h0 = f2bf_bits((v[0] - mu) * inv * gg[0] + bb[0]);
    unsigned short h1 = f2bf_bits((v[1] - mu) * inv * gg[1] + bb[1]);
    unsigned short h2 = f2bf_bits((v[2] - mu) * inv * gg[2] + bb[2]);
    unsigned short h3 = f2bf_bits((v[3] - mu) * inv * gg[3] + bb[3]);
    uint2 uu;
    uu.x = (unsigned)h0 | ((unsigned)h1 << 16);
    uu.y = (unsigned)h2 | ((unsigned)h3 << 16);
    *(uint2*)&out[row * D_ + lane * 4] = uu;
}

// ---------------------------------------------------------------------------
// MFMA GEMM v3: C[M,N] = A[M,K](bf16) @ Bt[N,K](bf16)^T + bias.
// BM=128, BN=64/128 (template), BK=64. 4 waves, each owns 32 x BN of output
// (2 m-frags x NT n-frags -> 16/32 MFMA per barrier pair). Staging is
// v1-style direct global->LDS (transient regs, NO arrays held across
// barriers -> no scratch spill, the r7 failure mode).
// Accumulation order over K identical to v1 -> bit-identical outputs.
// mode 0: fp32 out, bias per col, optional res add
// mode 1: bf16 out, bias per col, optional gelu
// mode 2: bf16 out, bias per ROW (V^T via swapped operands)
// mode 3: fused Q+K rope epilogue (cols 0-255 = Q with 1/8 scale, 256-511 = K)
// ---------------------------------------------------------------------------
template<int BN>
__global__ __launch_bounds__(256) void gemm_mfma(
    const unsigned short* __restrict__ A, const unsigned short* __restrict__ Bt,
    const float* __restrict__ bias, const float* __restrict__ bias2,
    const float* __restrict__ res,
    float* __restrict__ outf, unsigned short* __restrict__ outb,
    const float* __restrict__ ropeC, const float* __restrict__ ropeS,
    int M, int N, int K, int mode, int do_gelu)
{
    constexpr int NT = BN / 16;     // n-fragments per wave
    __shared__ __align__(16) short As[128 * 72];
    __shared__ __align__(16) short Bs[BN * 72];

    int tid = threadIdx.x;
    int w = tid >> 6, lane = tid & 63, quad = lane >> 4, l16 = lane & 15;
    int n0 = blockIdx.x * BN, r0 = blockIdx.y * 128;

    float4_t acc[2][NT];
    for (int m = 0; m < 2; ++m)
        for (int nt = 0; nt < NT; ++nt) acc[m][nt] = (float4_t){0.f, 0.f, 0.f, 0.f};

    for (int k0 = 0; k0 < K; k0 += 64) {
        __syncthreads();
        for (int i = 0; i < 4; ++i) {         // A: 128 rows x 8 chunks
            int e = tid + 256 * i, row = e >> 3, c8 = e & 7;
            *(short8_t*)&As[row * 72 + c8 * 8] =
                *(const short8_t*)&A[(long)(r0 + row) * K + k0 + c8 * 8];
        }
        for (int i = 0; i < BN / 32; ++i) {   // B: BN rows x 8 chunks
            int e = tid + 256 * i, row = e >> 3, c8 = e & 7;
            *(short8_t*)&Bs[row * 72 + c8 * 8] =
                *(const short8_t*)&Bt[(long)(n0 + row) * K + k0 + c8 * 8];
        }
        __syncthreads();
        for (int kq = 0; kq < 2; ++kq) {
            short8_t bf[NT];
            for (int nt = 0; nt < NT; ++nt)
                bf[nt] = *(const short8_t*)&Bs[(nt * 16 + l16) * 72 + kq * 32 + quad * 8];
            for (int m = 0; m < 2; ++m) {
                short8_t a = *(const short8_t*)&As[(w * 32 + m * 16 + l16) * 72 + kq * 32 + quad * 8];
                for (int nt = 0; nt < NT; ++nt)
                    acc[m][nt] = MFMA16(a, bf[nt], acc[m][nt]);
            }
        }
    }

    for (int m = 0; m < 2; ++m) {
        for (int nt = 0; nt < NT; ++nt) {
            int n = n0 + nt * 16 + l16;
            for (int r = 0; r < 4; ++r) {
                int row = r0 + w * 32 + m * 16 + quad * 4 + r;
                float v = acc[m][nt][r];
                if (mode == 2)      v += bias[row];
                else if (mode == 3) v += (n < 256) ? bias[n] : bias2[n - 256];
                else                v += bias[n];
                if (res) v += res[(long)row * N + n];
                if (do_gelu) v = 0.5f * v * (1.0f + erff(v * 0.70710678118654752f));
                if (mode == 0) {
                    outf[(long)row * N + n] = v;
                } else if (mode <= 2) {
                    outb[(long)row * N + n] = f2bf_bits(v);
                } else {   // mode 3: rope (pairs adjacent cols -> lane^1)
                    float vp = __shfl_xor(v, 1);
                    bool isK = (n >= 256);
                    int nn = isK ? n - 256 : n;
                    int bb = row >> 11, t = row & (T_ - 1);
                    int hh = nn >> 6, nb = (nn & 63) >> 1;
                    long ci = ((long)(bb * H_ + hh) * T_ + t) * NB_ + nb;
                    float c = ropeC[ci], sn = ropeS[ci];
                    float ov = (l16 & 1) ? (vp * sn + v * c) : (v * c - vp * sn);
                    float qs = isK ? 1.0f : 0.125f;
                    long off = isK ? (long)B_ * T_ * D_ : 0;
                    outb[off + ((long)(bb * H_ + hh) * T_ + t) * DH_ + (nn & 63)] =
                        f2bf_bits(ov * qs);
                }
            }
        }
    }
}

// ---------------------------------------------------------------------------
// MFMA flash attention v6: LDS-SHARED K/V tiles (unchanged from r6 winner).
// ---------------------------------------------------------------------------
__global__ __launch_bounds__(512) void attn_mfma(
    const unsigned short* __restrict__ Qb, const unsigned short* __restrict__ Kb,
    const unsigned short* __restrict__ Vt, unsigned short* __restrict__ O)
{
    __shared__ __align__(16) short KsS[2][64 * 72];
    __shared__ __align__(16) short VsS[2][64 * 72];
    union PsOm { short Ps[8][16 * 72]; float Om[4][16 * 66]; };
    __shared__ __align__(16) PsOm U;
    __shared__ float Ml[4][16][2];

    int tid = threadIdx.x;
    int w = tid >> 6, lane = tid & 63;
    int quad = lane >> 4, l16 = lane & 15;
    int bh = blockIdx.x & 15;
    int p  = blockIdx.x >> 4;            // 0..15
    int wr = w & 3;
    int g  = w >> 2;                     // 0 = group A, 1 = group B
    int b = bh >> 2, h = bh & 3;
    int qtS = 31 - p;                    // shared tile

    const unsigned short* kgb = Kb + (long)bh * T_ * DH_;
    const unsigned short* vgb = Vt + (long)h * DH_ * (B_ * T_) + (long)b * T_;
    short* PsW = &U.Ps[w][0];

    int row0 = wr * 16 + (lane >> 3);    // staging row (this lane, i=0)
    int c80  = (lane & 7) * 8;           // staging col offset (shorts)

    // initial Q frags
    int q0 = (g == 0 ? p : qtS) * 64;
    int qglob = q0 + wr * 16 + l16;
    const unsigned short* qp =
        Qb + ((long)bh * T_ + q0 + wr * 16 + l16) * DH_ + quad * 8;
    short8_t aq[2];
    aq[0] = *(const short8_t*)qp;
    aq[1] = *(const short8_t*)(qp + 32);

    float m_r = -3.0e38f, l_r = 0.0f;
    float4_t o[4];
    for (int nt = 0; nt < 4; ++nt) o[nt] = (float4_t){0.f, 0.f, 0.f, 0.f};

    // prologue: stage lap-0 tiles
    {
        int k0n = (g == 0) ? 0 : (16 - p) * 64;
        for (int i = 0; i < 2; ++i) {
            int row = row0 + 8 * i;
            short8_t kv = *(const short8_t*)&kgb[(long)(k0n + row) * DH_ + c80];
            short8_t vv = *(const short8_t*)&vgb[(long)row * (B_ * T_) + k0n + c80];
            *(short8_t*)&KsS[g][row * 72 + c80] = kv;
            *(short8_t*)&VsS[g][row * 72 + c80] = vv;
        }
    }
    __syncthreads();

    for (int j = 0; j < 17; ++j) {
        bool idle  = (g == 1) && (j == 16);
        bool haveN = (j < 16) && !((g == 1) && (j == 15));

        // issue next-lap global loads into registers (latency hides under compute)
        short8_t stK[2], stV[2];
        if (haveN) {
            int jn = j + 1;
            int k0n = (g == 0) ? ((jn <= p) ? jn * 64 : (jn - p - 1) * 64)
                               : (16 - p + jn) * 64;
            for (int i = 0; i < 2; ++i) {
                int row = row0 + 8 * i;
                stK[i] = *(const short8_t*)&kgb[(long)(k0n + row) * DH_ + c80];
                stV[i] = *(const short8_t*)&vgb[(long)row * (B_ * T_) + k0n + c80];
            }
        }

        if (!idle) {
            int k0 = (g == 0) ? ((j <= p) ? j * 64 : (j - p - 1) * 64)
                              : (16 - p + j) * 64;
            bool msk = (g == 0) ? (j == p) : (j == 15);

            // fragments from shared LDS tiles
            short8_t kf[4][2], vb[4][2];
            for (int nt = 0; nt < 4; ++nt) {
                const short* kb_ = &KsS[g][(nt * 16 + l16) * 72 + quad * 8];
                const short* vb_ = &VsS[g][(nt * 16 + l16) * 72 + quad * 8];
                kf[nt][0] = *(const short8_t*)kb_;
                kf[nt][1] = *(const short8_t*)(kb_ + 32);
                vb[nt][0] = *(const short8_t*)vb_;
                vb[nt][1] = *(const short8_t*)(vb_ + 32);
            }

            // S^T = K Q^T: lane holds S[k = nt*16+quad*4+r][q = l16]
            float4_t st[4];
            for (int nt = 0; nt < 4; ++nt) {
                float4_t sa = (float4_t){0.f, 0.f, 0.f, 0.f};
                sa = MFMA16(kf[nt][0], aq[0], sa);
                sa = MFMA16(kf[nt][1], aq[1], sa);
                st[nt] = sa;
            }

            // causal mask (last tile of masked segment) + in-lane max
            float mt = -3.0e38f;
            for (int nt = 0; nt < 4; ++nt) {
                for (int r = 0; r < 4; ++r) {
                    float sv = st[nt][r];
                    if (msk && (k0 + nt * 16 + quad * 4 + r) > qglob) sv = -3.0e38f;
                    st[nt][r] = sv;
                    mt = fmaxf(mt, sv);
                }
            }
            mt = fmaxf(mt, __shfl_xor(mt, 16));
            mt = fmaxf(mt, __shfl_xor(mt, 32));

            float mn = fmaxf(m_r, mt);
            float alpha = __expf(m_r - mn);
            m_r = mn;

            float ac[4];
            for (int r = 0; r < 4; ++r) ac[r] = __shfl(alpha, quad * 4 + r);

            float lt = 0.0f;
            for (int nt = 0; nt < 4; ++nt) {
                for (int r = 0; r < 4; ++r) {
                    float pv = __expf(st[nt][r] - m_r);
                    lt += pv;
                    PsW[l16 * 72 + nt * 16 + quad * 4 + r] = (short)f2bf_bits(pv);
                }
            }
            lt += __shfl_xor(lt, 16);
            lt += __shfl_xor(lt, 32);
            l_r = l_r * alpha + lt;

            for (int nt = 0; nt < 4; ++nt)
                for (int r = 0; r < 4; ++r) o[nt][r] *= ac[r];

            // O += P @ V (wave-private P strip)
            for (int kq = 0; kq < 2; ++kq) {
                short8_t pa = *(const short8_t*)&PsW[l16 * 72 + kq * 32 + quad * 8];
                for (int nt = 0; nt < 4; ++nt)
                    o[nt] = MFMA16(pa, vb[nt][kq], o[nt]);
            }

            // A-group transition: finalize tile p, switch to shared tile
            if (g == 0 && j == p) {
                float linv[4];
                for (int r = 0; r < 4; ++r) linv[r] = __shfl(l_r, quad * 4 + r);
                for (int r = 0; r < 4; ++r) {
                    float inv = 1.0f / linv[r];
                    int trow = p * 64 + wr * 16 + quad * 4 + r;
                    long orow = ((long)b * T_ + trow) * D_ + h * 64;
                    for (int nt = 0; nt < 4; ++nt)
                        O[orow + nt * 16 + l16] = f2bf_bits(o[nt][r] * inv);
                }
                m_r = -3.0e38f; l_r = 0.0f;
                for (int nt = 0; nt < 4; ++nt) o[nt] = (float4_t){0.f, 0.f, 0.f, 0.f};
                const unsigned short* qp2 =
                    Qb + ((long)bh * T_ + qtS * 64 + wr * 16 + l16) * DH_ + quad * 8;
                aq[0] = *(const short8_t*)qp2;
                aq[1] = *(const short8_t*)(qp2 + 32);
                qglob = qtS * 64 + wr * 16 + l16;   // unused (no mask in seg 2)
            }
        }

        if (j < 16) {
            __syncthreads();                 // all reads of current tiles done
            if (haveN) {
                for (int i = 0; i < 2; ++i) {
                    int row = row0 + 8 * i;
                    *(short8_t*)&KsS[g][row * 72 + c80] = stK[i];
                    *(short8_t*)&VsS[g][row * 72 + c80] = stV[i];
                }
            }
            __syncthreads();                 // next tiles visible
        }
    }

    __syncthreads();                         // lap-16 Ps reads done before stash
    if (g == 0) {
        for (int nt = 0; nt < 4; ++nt)
            for (int r = 0; r < 4; ++r)
                U.Om[wr][(quad * 4 + r) * 66 + nt * 16 + l16] = o[nt][r];
        if (quad == 0) { Ml[wr][l16][0] = m_r; Ml[wr][l16][1] = l_r; }
    }
    __syncthreads();
    if (g == 1) {
        int q0s = qtS * 64;
        for (int r = 0; r < 4; ++r) {
            int row = quad * 4 + r;
            float mA = Ml[wr][row][0], lA = Ml[wr][row][1];
            float mB = __shfl(m_r, row);
            float lB = __shfl(l_r, row);
            float M  = fmaxf(mA, mB);
            float eA = __expf(mA - M), eB = __expf(mB - M);
            float inv = 1.0f / (lA * eA + lB * eB);
            int trow = q0s + wr * 16 + row;
            long orow = ((long)b * T_ + trow) * D_ + h * 64;
            for (int nt = 0; nt < 4; ++nt) {
                float vm = U.Om[wr][row * 66 + nt * 16 + l16] * eA + o[nt][r] * eB;
                O[orow + nt * 16 + l16] = f2bf_bits(vm * inv);
            }
        }
    }
}

// ---------------------------------------------------------------------------
extern "C" void kernel_launch(void* const* d_in, const int* in_sizes, int n_in,
                              void* d_out, int out_size, void* d_ws, size_t ws_size,
                              hipStream_t stream)
{
    const int*   tokens    = (const int*)d_in[0];
    const float* token_emb = (const float*)d_in[1];
    const float* w_in      = (const float*)d_in[2];
    const float* w_out     = (const float*)d_in[3];
    const float* omega     = (const float*)d_in[4];
    const float* Wq        = (const float*)d_in[5];
    const float* bq        = (const float*)d_in[6];
    const float* Wk        = (const float*)d_in[7];
    const float* bk        = (const float*)d_in[8];
    const float* Wv        = (const float*)d_in[9];
    const float* bv        = (const float*)d_in[10];
    const float* Wo        = (const float*)d_in[11];
    const float* bo        = (const float*)d_in[12];
    const float* ln1_g     = (const float*)d_in[13];
    const float* ln1_b     = (const float*)d_in[14];
    const float* ln2_g     = (const float*)d_in[15];
    const float* ln2_b     = (const float*)d_in[16];
    const float* W1        = (const float*)d_in[17];
    const float* b1        = (const float*)d_in[18];
    const float* W2        = (const float*)d_in[19];
    const float* b2        = (const float*)d_in[20];
    const float* out_g     = (const float*)d_in[21];
    const float* out_b     = (const float*)d_in[22];
    const float* Wout      = (const float*)d_in[23];
    const float* bout      = (const float*)d_in[24];

    const long NTOK = (long)B_ * T_;  // 8192
    float* xbuf = (float*)d_ws;                       // fp32 residual stream 8MB
    float* cosb = xbuf + NTOK * D_;                   // (B,H,T,NB) fp32 4MB
    float* sinb = cosb + NTOK * H_ * NB_;             // 4MB
    float* dbuf = sinb + NTOK * H_ * NB_;             // (B,T,H*NB) fp32 4MB
    unsigned short* hbuf  = (unsigned short*)(dbuf + NTOK * H_ * NB_); // bf16 LN out 4MB
    unsigned short* obuf  = hbuf + NTOK * D_;         // bf16 attn out 4MB
    unsigned short* ffbuf = obuf + NTOK * D_;         // bf16 FFN mid 16MB
    unsigned short* qb16  = ffbuf + NTOK * DFF_;      // bf16 Q (B,H,T,DH) 4MB
    unsigned short* kb16  = qb16 + NTOK * D_;         // bf16 K (B,H,T,DH) 4MB (MUST follow qb16)
    unsigned short* vtb   = kb16 + NTOK * D_;         // bf16 V^T [H*DH][B*T] 4MB
    unsigned short* wqkt  = vtb + NTOK * D_;          // fused Q|K weights 2x131072
    unsigned short* wvt   = wqkt + 2 * 131072;
    unsigned short* wot   = wvt + 2 * 65536;
    unsigned short* w1t   = wot + 2 * 65536;
    unsigned short* w2t   = w1t + 2 * 262144;
    unsigned short* woutt = w2t + 2 * 262144;
    // total ~60 MB

    wt_kernel<<<1664, 256, 0, stream>>>(Wq, Wk, Wv, Wo, W1, W2, Wout,
                                        wqkt, wvt, wot, w1t, w2t, woutt);
    embed_kernel<<<NTOK, 256, 0, stream>>>(tokens, token_emb, w_in, w_out, xbuf, dbuf);
    cumsum_kernel<<<B_ * H_ * NB_, 256, 0, stream>>>(dbuf, omega, cosb, sinb);

    for (int l = 0; l < NL_; ++l) {
        ln_kernel<<<2048, 256, 0, stream>>>(xbuf, ln1_g + l * D_, ln1_b + l * D_, hbuf);
        // fused Q+K: rope + per-half scale/bias, bf16 attn layout
        gemm_mfma<128><<<dim3(4, 64), 256, 0, stream>>>(
            hbuf, wqkt + (long)l * 131072, bq + l * D_, bk + l * D_, nullptr,
            nullptr, qb16, cosb, sinb, (int)NTOK, 512, 256, 3, 0);
        // V^T via swapped operands: C[d][token] = sum_k Wv[k][d] h[token][k]
        gemm_mfma<64><<<dim3(128, 2), 256, 0, stream>>>(
            wvt + (long)l * 65536, hbuf, bv + l * D_, nullptr, nullptr,
            nullptr, vtb, nullptr, nullptr, 256, (int)NTOK, 256, 2, 0);
        attn_mfma<<<256, 512, 0, stream>>>(qb16, kb16, vtb, obuf);
        gemm_mfma<64><<<dim3(4, 64), 256, 0, stream>>>(
            obuf, wot + (long)l * 65536, bo + l * D_, nullptr, xbuf,
            xbuf, nullptr, nullptr, nullptr, (int)NTOK, 256, 256, 0, 0);
        ln_kernel<<<2048, 256, 0, stream>>>(xbuf, ln2_g + l * D_, ln2_b + l * D_, hbuf);
        gemm_mfma<128><<<dim3(8, 64), 256, 0, stream>>>(
            hbuf, w1t + (long)l * 262144, b1 + l * DFF_, nullptr, nullptr,
            nullptr, ffbuf, nullptr, nullptr, (int)NTOK, DFF_, 256, 1, 1);
        gemm_mfma<64><<<dim3(4, 64), 256, 0, stream>>>(
            ffbuf, w2t + (long)l * 262144, b2 + l * D_, nullptr, xbuf,
            xbuf, nullptr, nullptr, nullptr, (int)NTOK, 256, 1024, 0, 0);
    }

    ln_kernel<<<2048, 256, 0, stream>>>(xbuf, out_g, out_b, hbuf);
    gemm_mfma<128><<<dim3(4, 64), 256, 0, stream>>>(
        hbuf, woutt, bout, nullptr, nullptr,
        (float*)d_out, nullptr, nullptr, nullptr, (int)NTOK, V_, 256, 0, 0);
}

// Round 9
// 391.459 us; speedup vs baseline: 1.7982x; 1.7982x over previous
//
#include <hip/hip_runtime.h>
#include <hip/hip_bf16.h>
#include <math.h>

#define B_   4
#define T_   2048
#define V_   512
#define D_   256
#define H_   4
#define DH_  64
#define NB_  32
#define DFF_ 1024
#define NL_  2

typedef __attribute__((ext_vector_type(8))) short short8_t;
typedef __attribute__((ext_vector_type(4))) float float4_t;

#define MFMA16(a,b,c) __builtin_amdgcn_mfma_f32_16x16x32_bf16(a,b,c,0,0,0)

__device__ __forceinline__ unsigned short f2bf_bits(float f) {
    unsigned u = __float_as_uint(f);
    u += 0x7fffu + ((u >> 16) & 1u);
    return (unsigned short)(u >> 16);
}

// ---------------------------------------------------------------------------
// Weight transpose+cast: W[K][N] fp32 -> Wt[N][K] bf16. One 32x32 tile/block.
// Wq/Wk land in a fused wqkt buffer: [layer][512][256] (Q rows 0-255, K 256-511)
// ---------------------------------------------------------------------------
__global__ __launch_bounds__(256) void wt_kernel(
    const float* __restrict__ Wq, const float* __restrict__ Wk,
    const float* __restrict__ Wv, const float* __restrict__ Wo,
    const float* __restrict__ W1, const float* __restrict__ W2,
    const float* __restrict__ Wout,
    unsigned short* __restrict__ wqkt,
    unsigned short* __restrict__ wvt, unsigned short* __restrict__ wot,
    unsigned short* __restrict__ w1t, unsigned short* __restrict__ w2t,
    unsigned short* __restrict__ woutt)
{
    __shared__ float tile[32][33];
    int bx = blockIdx.x, tid = threadIdx.x;
    const float* src; unsigned short* dst; int Kd, Nd, tr, tc;
    if (bx < 512) {                    // Wq/Wk/Wv/Wo, 2 layers each, 256x256
        int am = bx >> 6, t = bx & 63;
        int m4 = am >> 1, layer = am & 1;
        const float* s4[4] = {Wq, Wk, Wv, Wo};
        src = s4[m4] + (long)layer * 65536;
        if (m4 == 0)      dst = wqkt + (long)layer * 131072;
        else if (m4 == 1) dst = wqkt + (long)layer * 131072 + 65536;
        else if (m4 == 2) dst = wvt + (long)layer * 65536;
        else              dst = wot + (long)layer * 65536;
        Kd = 256; Nd = 256; tr = t >> 3; tc = t & 7;
    } else if (bx < 1024) {            // W1: 2 x (256x1024)
        int idx = bx - 512, mat = idx >> 8, t = idx & 255;
        src = W1 + (long)mat * 262144; dst = w1t + (long)mat * 262144;
        Kd = 256; Nd = 1024; tr = t >> 5; tc = t & 31;
    } else if (bx < 1536) {            // W2: 2 x (1024x256)
        int idx = bx - 1024, mat = idx >> 8, t = idx & 255;
        src = W2 + (long)mat * 262144; dst = w2t + (long)mat * 262144;
        Kd = 1024; Nd = 256; tr = t >> 3; tc = t & 7;
    } else {                           // Wout: 256x512
        int t = bx - 1536;
        src = Wout; dst = woutt; Kd = 256; Nd = 512; tr = t >> 4; tc = t & 15;
    }
    int kr = tid >> 3, nc4 = (tid & 7) * 4;
    float4_t v = *(const float4_t*)&src[(long)(tr * 32 + kr) * Nd + tc * 32 + nc4];
    for (int j = 0; j < 4; ++j) tile[kr][nc4 + j] = v[j];
    __syncthreads();
    int nr = tid >> 3, kc4 = (tid & 7) * 4;
    unsigned short tmp[4];
    for (int j = 0; j < 4; ++j) tmp[j] = f2bf_bits(tile[kc4 + j][nr]);
    uint2 uu;
    uu.x = (unsigned)tmp[0] | ((unsigned)tmp[1] << 16);
    uu.y = (unsigned)tmp[2] | ((unsigned)tmp[3] << 16);
    *(uint2*)&dst[(long)(tc * 32 + nr) * Kd + tr * 32 + kc4] = uu;
}

// ---------------------------------------------------------------------------
// Token embedding gather + rank-2 delta projection
// ---------------------------------------------------------------------------
__global__ __launch_bounds__(256) void embed_kernel(
    const int* __restrict__ tokens, const float* __restrict__ emb,
    const float* __restrict__ w_in, const float* __restrict__ w_out,
    float* __restrict__ x, float* __restrict__ delta)
{
    int bt = blockIdx.x;
    int d  = threadIdx.x;
    int tok = tokens[bt];
    float e = emb[tok * D_ + d];
    x[(long)bt * D_ + d] = e;

    __shared__ float r0s[256], r1s[256];
    r0s[d] = e * w_in[d * 2 + 0];
    r1s[d] = e * w_in[d * 2 + 1];
    __syncthreads();
    for (int off = 128; off > 0; off >>= 1) {
        if (d < off) { r0s[d] += r0s[d + off]; r1s[d] += r1s[d + off]; }
        __syncthreads();
    }
    float r0 = r0s[0], r1 = r1s[0];
    if (d < H_ * NB_) {
        delta[(long)bt * (H_ * NB_) + d] =
            r0 * w_out[d] + r1 * w_out[H_ * NB_ + d];
    }
}

// ---------------------------------------------------------------------------
// cumsum over T per (b, channel) + cos/sin
// ---------------------------------------------------------------------------
__global__ __launch_bounds__(256) void cumsum_kernel(
    const float* __restrict__ delta, const float* __restrict__ omega,
    float* __restrict__ cosb, float* __restrict__ sinb)
{
    int c = blockIdx.x & (H_ * NB_ - 1);
    int b = blockIdx.x >> 7;
    int tid = threadIdx.x;
    float om = omega[c];
    int h = c >> 5, nb = c & (NB_ - 1);

    float vals[8];
    float s = 0.0f;
    for (int i = 0; i < 8; ++i) {
        int t = tid * 8 + i;
        vals[i] = delta[((long)b * T_ + t) * (H_ * NB_) + c];
        s += vals[i];
    }
    __shared__ float sc[256];
    sc[tid] = s;
    __syncthreads();
    for (int off = 1; off < 256; off <<= 1) {
        float v = (tid >= off) ? sc[tid - off] : 0.0f;
        __syncthreads();
        sc[tid] += v;
        __syncthreads();
    }
    float run = sc[tid] - s;
    for (int i = 0; i < 8; ++i) {
        run += vals[i];
        float ang = run * om;
        int t = tid * 8 + i;
        long oi = ((long)(b * H_ + h) * T_ + t) * NB_ + nb;
        cosb[oi] = cosf(ang);
        sinb[oi] = sinf(ang);
    }
}

// ---------------------------------------------------------------------------
// LayerNorm (fp32 in) -> bf16 out. Wave-per-row, no LDS, no barriers.
// ---------------------------------------------------------------------------
__global__ __launch_bounds__(256) void ln_kernel(
    const float* __restrict__ x, const float* __restrict__ g,
    const float* __restrict__ b, unsigned short* __restrict__ out)
{
    int w = threadIdx.x >> 6, lane = threadIdx.x & 63;
    long row = (long)blockIdx.x * 4 + w;
    float4_t v = *(const float4_t*)&x[row * D_ + lane * 4];
    float s = v[0] + v[1] + v[2] + v[3];
    float q = v[0]*v[0] + v[1]*v[1] + v[2]*v[2] + v[3]*v[3];
    for (int off = 1; off < 64; off <<= 1) {
        s += __shfl_xor(s, off);
        q += __shfl_xor(q, off);
    }
    float mu  = s * (1.0f / D_);
    float var = q * (1.0f / D_) - mu * mu;
    float inv = rsqrtf(var + 1e-5f);
    float4_t gg = *(const float4_t*)&g[lane * 4];
    float4_t bb = *(const float4_t*)&b[lane * 4];
    unsigned short h0 = f2bf_bits((v[0] - mu) * inv * gg[0] + bb[0]);
    unsigned short h1 = f2bf_bits((v[1] - mu) * inv * gg[1] + bb[1]);
    unsigned short h2 = f2bf_bits((v[2] - mu) * inv * gg[2] + bb[2]);
    unsigned short h3 = f2bf_bits((v[3] - mu) * inv * gg[3] + bb[3]);
    uint2 uu;
    uu.x = (unsigned)h0 | ((unsigned)h1 << 16);
    uu.y = (unsigned)h2 | ((unsigned)h3 << 16);
    *(uint2*)&out[row * D_ + lane * 4] = uu;
}

// ---------------------------------------------------------------------------
// MFMA GEMM v4: r6's proven v1 engine (BM=64, BN=64, BK=64, 4 waves x 16x64,
// grids >= 512 blocks = >= 2 blocks/CU) + the attention-v6 lap structure:
// double-buffered LDS with single-tile register prefetch. Per K-step:
//   issue tile k+1 global loads (held ~32 VGPRs, like attn v6's stK/stV)
//   compute tile k from LDS[cur] (8 MFMAs)
//   barrier; write prefetch regs -> LDS[cur^1]; barrier
// Global-load latency lands under the MFMA block. Accumulation order over K
// identical to v1 -> bit-identical outputs.
// mode 0: fp32 out, bias per col, optional res add
// mode 1: bf16 out, bias per col, optional gelu
// mode 2: bf16 out, bias per ROW (V^T via swapped operands)
// mode 3: fused Q+K rope epilogue (cols 0-255 = Q with 1/8 scale, 256-511 = K)
// ---------------------------------------------------------------------------
__global__ __launch_bounds__(256) void gemm_mfma(
    const unsigned short* __restrict__ A, const unsigned short* __restrict__ Bt,
    const float* __restrict__ bias, const float* __restrict__ bias2,
    const float* __restrict__ res,
    float* __restrict__ outf, unsigned short* __restrict__ outb,
    const float* __restrict__ ropeC, const float* __restrict__ ropeS,
    int M, int N, int K, int mode, int do_gelu)
{
    __shared__ __align__(16) short As[2][64 * 72];
    __shared__ __align__(16) short Bs[2][64 * 72];
    int tid = threadIdx.x;
    int w = tid >> 6, lane = tid & 63, quad = lane >> 4, l16 = lane & 15;
    int n0 = blockIdx.x * 64, r0 = blockIdx.y * 64;

    float4_t acc[4];
    for (int nt = 0; nt < 4; ++nt) acc[nt] = (float4_t){0.f, 0.f, 0.f, 0.f};

    // stage tile 0 into buffer 0 (transient regs)
    for (int i = 0; i < 2; ++i) {
        int e = tid + 256 * i, row = e >> 3, c8 = e & 7;
        *(short8_t*)&As[0][row * 72 + c8 * 8] =
            *(const short8_t*)&A[(long)(r0 + row) * K + c8 * 8];
        *(short8_t*)&Bs[0][row * 72 + c8 * 8] =
            *(const short8_t*)&Bt[(long)(n0 + row) * K + c8 * 8];
    }
    __syncthreads();

    int cur = 0;
    for (int k0 = 0; k0 < K; k0 += 64) {
        bool have = (k0 + 64 < K);
        // prefetch tile k+1 into registers (in flight during MFMAs below)
        short8_t pA[2], pB[2];
        if (have) {
            for (int i = 0; i < 2; ++i) {
                int e = tid + 256 * i, row = e >> 3, c8 = e & 7;
                pA[i] = *(const short8_t*)&A[(long)(r0 + row) * K + k0 + 64 + c8 * 8];
                pB[i] = *(const short8_t*)&Bt[(long)(n0 + row) * K + k0 + 64 + c8 * 8];
            }
        }
        // compute tile k from LDS[cur]
        for (int kq = 0; kq < 2; ++kq) {
            short8_t a = *(const short8_t*)&As[cur][(w * 16 + l16) * 72 + kq * 32 + quad * 8];
            for (int nt = 0; nt < 4; ++nt) {
                short8_t bfr = *(const short8_t*)&Bs[cur][(nt * 16 + l16) * 72 + kq * 32 + quad * 8];
                acc[nt] = MFMA16(a, bfr, acc[nt]);
            }
        }
        if (have) {
            __syncthreads();     // prior-iteration readers of LDS[cur^1] done
            for (int i = 0; i < 2; ++i) {
                int e = tid + 256 * i, row = e >> 3, c8 = e & 7;
                *(short8_t*)&As[cur ^ 1][row * 72 + c8 * 8] = pA[i];
                *(short8_t*)&Bs[cur ^ 1][row * 72 + c8 * 8] = pB[i];
            }
            __syncthreads();     // next tile visible to all waves
            cur ^= 1;
        }
    }

    for (int nt = 0; nt < 4; ++nt) {
        int n = n0 + nt * 16 + l16;
        for (int r = 0; r < 4; ++r) {
            int row = r0 + w * 16 + quad * 4 + r;
            float v = acc[nt][r];
            if (mode == 2)      v += bias[row];
            else if (mode == 3) v += (n < 256) ? bias[n] : bias2[n - 256];
            else                v += bias[n];
            if (res) v += res[(long)row * N + n];
            if (do_gelu) v = 0.5f * v * (1.0f + erff(v * 0.70710678118654752f));
            if (mode == 0) {
                outf[(long)row * N + n] = v;
            } else if (mode <= 2) {
                outb[(long)row * N + n] = f2bf_bits(v);
            } else {   // mode 3: rope (pairs adjacent cols -> lane^1)
                float vp = __shfl_xor(v, 1);
                bool isK = (n >= 256);
                int nn = isK ? n - 256 : n;
                int bb = row >> 11, t = row & (T_ - 1);
                int hh = nn >> 6, nb = (nn & 63) >> 1;
                long ci = ((long)(bb * H_ + hh) * T_ + t) * NB_ + nb;
                float c = ropeC[ci], sn = ropeS[ci];
                float ov = (l16 & 1) ? (vp * sn + v * c) : (v * c - vp * sn);
                float qs = isK ? 1.0f : 0.125f;
                long off = isK ? (long)B_ * T_ * D_ : 0;
                outb[off + ((long)(bb * H_ + hh) * T_ + t) * DH_ + (nn & 63)] =
                    f2bf_bits(ov * qs);
            }
        }
    }
}

// ---------------------------------------------------------------------------
// MFMA flash attention v6: LDS-SHARED K/V tiles (unchanged from r6 winner).
// ---------------------------------------------------------------------------
__global__ __launch_bounds__(512) void attn_mfma(
    const unsigned short* __restrict__ Qb, const unsigned short* __restrict__ Kb,
    const unsigned short* __restrict__ Vt, unsigned short* __restrict__ O)
{
    __shared__ __align__(16) short KsS[2][64 * 72];
    __shared__ __align__(16) short VsS[2][64 * 72];
    union PsOm { short Ps[8][16 * 72]; float Om[4][16 * 66]; };
    __shared__ __align__(16) PsOm U;
    __shared__ float Ml[4][16][2];

    int tid = threadIdx.x;
    int w = tid >> 6, lane = tid & 63;
    int quad = lane >> 4, l16 = lane & 15;
    int bh = blockIdx.x & 15;
    int p  = blockIdx.x >> 4;            // 0..15
    int wr = w & 3;
    int g  = w >> 2;                     // 0 = group A, 1 = group B
    int b = bh >> 2, h = bh & 3;
    int qtS = 31 - p;                    // shared tile

    const unsigned short* kgb = Kb + (long)bh * T_ * DH_;
    const unsigned short* vgb = Vt + (long)h * DH_ * (B_ * T_) + (long)b * T_;
    short* PsW = &U.Ps[w][0];

    int row0 = wr * 16 + (lane >> 3);    // staging row (this lane, i=0)
    int c80  = (lane & 7) * 8;           // staging col offset (shorts)

    // initial Q frags
    int q0 = (g == 0 ? p : qtS) * 64;
    int qglob = q0 + wr * 16 + l16;
    const unsigned short* qp =
        Qb + ((long)bh * T_ + q0 + wr * 16 + l16) * DH_ + quad * 8;
    short8_t aq[2];
    aq[0] = *(const short8_t*)qp;
    aq[1] = *(const short8_t*)(qp + 32);

    float m_r = -3.0e38f, l_r = 0.0f;
    float4_t o[4];
    for (int nt = 0; nt < 4; ++nt) o[nt] = (float4_t){0.f, 0.f, 0.f, 0.f};

    // prologue: stage lap-0 tiles
    {
        int k0n = (g == 0) ? 0 : (16 - p) * 64;
        for (int i = 0; i < 2; ++i) {
            int row = row0 + 8 * i;
            short8_t kv = *(const short8_t*)&kgb[(long)(k0n + row) * DH_ + c80];
            short8_t vv = *(const short8_t*)&vgb[(long)row * (B_ * T_) + k0n + c80];
            *(short8_t*)&KsS[g][row * 72 + c80] = kv;
            *(short8_t*)&VsS[g][row * 72 + c80] = vv;
        }
    }
    __syncthreads();

    for (int j = 0; j < 17; ++j) {
        bool idle  = (g == 1) && (j == 16);
        bool haveN = (j < 16) && !((g == 1) && (j == 15));

        // issue next-lap global loads into registers (latency hides under compute)
        short8_t stK[2], stV[2];
        if (haveN) {
            int jn = j + 1;
            int k0n = (g == 0) ? ((jn <= p) ? jn * 64 : (jn - p - 1) * 64)
                               : (16 - p + jn) * 64;
            for (int i = 0; i < 2; ++i) {
                int row = row0 + 8 * i;
                stK[i] = *(const short8_t*)&kgb[(long)(k0n + row) * DH_ + c80];
                stV[i] = *(const short8_t*)&vgb[(long)row * (B_ * T_) + k0n + c80];
            }
        }

        if (!idle) {
            int k0 = (g == 0) ? ((j <= p) ? j * 64 : (j - p - 1) * 64)
                              : (16 - p + j) * 64;
            bool msk = (g == 0) ? (j == p) : (j == 15);

            // fragments from shared LDS tiles
            short8_t kf[4][2], vb[4][2];
            for (int nt = 0; nt < 4; ++nt) {
                const short* kb_ = &KsS[g][(nt * 16 + l16) * 72 + quad * 8];
                const short* vb_ = &VsS[g][(nt * 16 + l16) * 72 + quad * 8];
                kf[nt][0] = *(const short8_t*)kb_;
                kf[nt][1] = *(const short8_t*)(kb_ + 32);
                vb[nt][0] = *(const short8_t*)vb_;
                vb[nt][1] = *(const short8_t*)(vb_ + 32);
            }

            // S^T = K Q^T: lane holds S[k = nt*16+quad*4+r][q = l16]
            float4_t st[4];
            for (int nt = 0; nt < 4; ++nt) {
                float4_t sa = (float4_t){0.f, 0.f, 0.f, 0.f};
                sa = MFMA16(kf[nt][0], aq[0], sa);
                sa = MFMA16(kf[nt][1], aq[1], sa);
                st[nt] = sa;
            }

            // causal mask (last tile of masked segment) + in-lane max
            float mt = -3.0e38f;
            for (int nt = 0; nt < 4; ++nt) {
                for (int r = 0; r < 4; ++r) {
                    float sv = st[nt][r];
                    if (msk && (k0 + nt * 16 + quad * 4 + r) > qglob) sv = -3.0e38f;
                    st[nt][r] = sv;
                    mt = fmaxf(mt, sv);
                }
            }
            mt = fmaxf(mt, __shfl_xor(mt, 16));
            mt = fmaxf(mt, __shfl_xor(mt, 32));

            float mn = fmaxf(m_r, mt);
            float alpha = __expf(m_r - mn);
            m_r = mn;

            float ac[4];
            for (int r = 0; r < 4; ++r) ac[r] = __shfl(alpha, quad * 4 + r);

            float lt = 0.0f;
            for (int nt = 0; nt < 4; ++nt) {
                for (int r = 0; r < 4; ++r) {
                    float pv = __expf(st[nt][r] - m_r);
                    lt += pv;
                    PsW[l16 * 72 + nt * 16 + quad * 4 + r] = (short)f2bf_bits(pv);
                }
            }
            lt += __shfl_xor(lt, 16);
            lt += __shfl_xor(lt, 32);
            l_r = l_r * alpha + lt;

            for (int nt = 0; nt < 4; ++nt)
                for (int r = 0; r < 4; ++r) o[nt][r] *= ac[r];

            // O += P @ V (wave-private P strip)
            for (int kq = 0; kq < 2; ++kq) {
                short8_t pa = *(const short8_t*)&PsW[l16 * 72 + kq * 32 + quad * 8];
                for (int nt = 0; nt < 4; ++nt)
                    o[nt] = MFMA16(pa, vb[nt][kq], o[nt]);
            }

            // A-group transition: finalize tile p, switch to shared tile
            if (g == 0 && j == p) {
                float linv[4];
                for (int r = 0; r < 4; ++r) linv[r] = __shfl(l_r, quad * 4 + r);
                for (int r = 0; r < 4; ++r) {
                    float inv = 1.0f / linv[r];
                    int trow = p * 64 + wr * 16 + quad * 4 + r;
                    long orow = ((long)b * T_ + trow) * D_ + h * 64;
                    for (int nt = 0; nt < 4; ++nt)
                        O[orow + nt * 16 + l16] = f2bf_bits(o[nt][r] * inv);
                }
                m_r = -3.0e38f; l_r = 0.0f;
                for (int nt = 0; nt < 4; ++nt) o[nt] = (float4_t){0.f, 0.f, 0.f, 0.f};
                const unsigned short* qp2 =
                    Qb + ((long)bh * T_ + qtS * 64 + wr * 16 + l16) * DH_ + quad * 8;
                aq[0] = *(const short8_t*)qp2;
                aq[1] = *(const short8_t*)(qp2 + 32);
                qglob = qtS * 64 + wr * 16 + l16;   // unused (no mask in seg 2)
            }
        }

        if (j < 16) {
            __syncthreads();                 // all reads of current tiles done
            if (haveN) {
                for (int i = 0; i < 2; ++i) {
                    int row = row0 + 8 * i;
                    *(short8_t*)&KsS[g][row * 72 + c80] = stK[i];
                    *(short8_t*)&VsS[g][row * 72 + c80] = stV[i];
                }
            }
            __syncthreads();                 // next tiles visible
        }
    }

    __syncthreads();                         // lap-16 Ps reads done before stash
    if (g == 0) {
        for (int nt = 0; nt < 4; ++nt)
            for (int r = 0; r < 4; ++r)
                U.Om[wr][(quad * 4 + r) * 66 + nt * 16 + l16] = o[nt][r];
        if (quad == 0) { Ml[wr][l16][0] = m_r; Ml[wr][l16][1] = l_r; }
    }
    __syncthreads();
    if (g == 1) {
        int q0s = qtS * 64;
        for (int r = 0; r < 4; ++r) {
            int row = quad * 4 + r;
            float mA = Ml[wr][row][0], lA = Ml[wr][row][1];
            float mB = __shfl(m_r, row);
            float lB = __shfl(l_r, row);
            float M  = fmaxf(mA, mB);
            float eA = __expf(mA - M), eB = __expf(mB - M);
            float inv = 1.0f / (lA * eA + lB * eB);
            int trow = q0s + wr * 16 + row;
            long orow = ((long)b * T_ + trow) * D_ + h * 64;
            for (int nt = 0; nt < 4; ++nt) {
                float vm = U.Om[wr][row * 66 + nt * 16 + l16] * eA + o[nt][r] * eB;
                O[orow + nt * 16 + l16] = f2bf_bits(vm * inv);
            }
        }
    }
}

// ---------------------------------------------------------------------------
extern "C" void kernel_launch(void* const* d_in, const int* in_sizes, int n_in,
                              void* d_out, int out_size, void* d_ws, size_t ws_size,
                              hipStream_t stream)
{
    const int*   tokens    = (const int*)d_in[0];
    const float* token_emb = (const float*)d_in[1];
    const float* w_in      = (const float*)d_in[2];
    const float* w_out     = (const float*)d_in[3];
    const float* omega     = (const float*)d_in[4];
    const float* Wq        = (const float*)d_in[5];
    const float* bq        = (const float*)d_in[6];
    const float* Wk        = (const float*)d_in[7];
    const float* bk        = (const float*)d_in[8];
    const float* Wv        = (const float*)d_in[9];
    const float* bv        = (const float*)d_in[10];
    const float* Wo        = (const float*)d_in[11];
    const float* bo        = (const float*)d_in[12];
    const float* ln1_g     = (const float*)d_in[13];
    const float* ln1_b     = (const float*)d_in[14];
    const float* ln2_g     = (const float*)d_in[15];
    const float* ln2_b     = (const float*)d_in[16];
    const float* W1        = (const float*)d_in[17];
    const float* b1        = (const float*)d_in[18];
    const float* W2        = (const float*)d_in[19];
    const float* b2        = (const float*)d_in[20];
    const float* out_g     = (const float*)d_in[21];
    const float* out_b     = (const float*)d_in[22];
    const float* Wout      = (const float*)d_in[23];
    const float* bout      = (const float*)d_in[24];

    const long NTOK = (long)B_ * T_;  // 8192
    float* xbuf = (float*)d_ws;                       // fp32 residual stream 8MB
    float* cosb = xbuf + NTOK * D_;                   // (B,H,T,NB) fp32 4MB
    float* sinb = cosb + NTOK * H_ * NB_;             // 4MB
    float* dbuf = sinb + NTOK * H_ * NB_;             // (B,T,H*NB) fp32 4MB
    unsigned short* hbuf  = (unsigned short*)(dbuf + NTOK * H_ * NB_); // bf16 LN out 4MB
    unsigned short* obuf  = hbuf + NTOK * D_;         // bf16 attn out 4MB
    unsigned short* ffbuf = obuf + NTOK * D_;         // bf16 FFN mid 16MB
    unsigned short* qb16  = ffbuf + NTOK * DFF_;      // bf16 Q (B,H,T,DH) 4MB
    unsigned short* kb16  = qb16 + NTOK * D_;         // bf16 K (B,H,T,DH) 4MB (MUST follow qb16)
    unsigned short* vtb   = kb16 + NTOK * D_;         // bf16 V^T [H*DH][B*T] 4MB
    unsigned short* wqkt  = vtb + NTOK * D_;          // fused Q|K weights 2x131072
    unsigned short* wvt   = wqkt + 2 * 131072;
    unsigned short* wot   = wvt + 2 * 65536;
    unsigned short* w1t   = wot + 2 * 65536;
    unsigned short* w2t   = w1t + 2 * 262144;
    unsigned short* woutt = w2t + 2 * 262144;
    // total ~60 MB

    wt_kernel<<<1664, 256, 0, stream>>>(Wq, Wk, Wv, Wo, W1, W2, Wout,
                                        wqkt, wvt, wot, w1t, w2t, woutt);
    embed_kernel<<<NTOK, 256, 0, stream>>>(tokens, token_emb, w_in, w_out, xbuf, dbuf);
    cumsum_kernel<<<B_ * H_ * NB_, 256, 0, stream>>>(dbuf, omega, cosb, sinb);

    for (int l = 0; l < NL_; ++l) {
        ln_kernel<<<2048, 256, 0, stream>>>(xbuf, ln1_g + l * D_, ln1_b + l * D_, hbuf);
        // fused Q+K: rope + per-half scale/bias, bf16 attn layout (1024 blocks)
        gemm_mfma<<<dim3(8, 128), 256, 0, stream>>>(
            hbuf, wqkt + (long)l * 131072, bq + l * D_, bk + l * D_, nullptr,
            nullptr, qb16, cosb, sinb, (int)NTOK, 512, 256, 3, 0);
        // V^T via swapped operands: C[d][token] = sum_k Wv[k][d] h[token][k]
        gemm_mfma<<<dim3(128, 4), 256, 0, stream>>>(
            wvt + (long)l * 65536, hbuf, bv + l * D_, nullptr, nullptr,
            nullptr, vtb, nullptr, nullptr, 256, (int)NTOK, 256, 2, 0);
        attn_mfma<<<256, 512, 0, stream>>>(qb16, kb16, vtb, obuf);
        gemm_mfma<<<dim3(4, 128), 256, 0, stream>>>(
            obuf, wot + (long)l * 65536, bo + l * D_, nullptr, xbuf,
            xbuf, nullptr, nullptr, nullptr, (int)NTOK, 256, 256, 0, 0);
        ln_kernel<<<2048, 256, 0, stream>>>(xbuf, ln2_g + l * D_, ln2_b + l * D_, hbuf);
        gemm_mfma<<<dim3(16, 128), 256, 0, stream>>>(
            hbuf, w1t + (long)l * 262144, b1 + l * DFF_, nullptr, nullptr,
            nullptr, ffbuf, nullptr, nullptr, (int)NTOK, DFF_, 256, 1, 1);
        gemm_mfma<<<dim3(4, 128), 256, 0, stream>>>(
            ffbuf, w2t + (long)l * 262144, b2 + l * D_, nullptr, xbuf,
            xbuf, nullptr, nullptr, nullptr, (int)NTOK, 256, 1024, 0, 0);
    }

    ln_kernel<<<2048, 256, 0, stream>>>(xbuf, out_g, out_b, hbuf);
    gemm_mfma<<<dim3(8, 128), 256, 0, stream>>>(
        hbuf, woutt, bout, nullptr, nullptr,
        (float*)d_out, nullptr, nullptr, nullptr, (int)NTOK, V_, 256, 0, 0);
}

// Round 10
// 385.430 us; speedup vs baseline: 1.8263x; 1.0156x over previous
//
#include <hip/hip_runtime.h>
#include <hip/hip_bf16.h>
#include <math.h>

#define B_   4
#define T_   2048
#define V_   512
#define D_   256
#define H_   4
#define DH_  64
#define NB_  32
#define DFF_ 1024
#define NL_  2

typedef __attribute__((ext_vector_type(8))) short short8_t;
typedef __attribute__((ext_vector_type(4))) float float4_t;

#define MFMA16(a,b,c) __builtin_amdgcn_mfma_f32_16x16x32_bf16(a,b,c,0,0,0)

__device__ __forceinline__ unsigned short f2bf_bits(float f) {
    unsigned u = __float_as_uint(f);
    u += 0x7fffu + ((u >> 16) & 1u);
    return (unsigned short)(u >> 16);
}

// ---------------------------------------------------------------------------
// Weight transpose+cast: W[K][N] fp32 -> Wt[N][K] bf16. One 32x32 tile/block.
// Wq/Wk land in a fused wqkt buffer: [layer][512][256] (Q rows 0-255, K 256-511)
// ---------------------------------------------------------------------------
__global__ __launch_bounds__(256) void wt_kernel(
    const float* __restrict__ Wq, const float* __restrict__ Wk,
    const float* __restrict__ Wv, const float* __restrict__ Wo,
    const float* __restrict__ W1, const float* __restrict__ W2,
    const float* __restrict__ Wout,
    unsigned short* __restrict__ wqkt,
    unsigned short* __restrict__ wvt, unsigned short* __restrict__ wot,
    unsigned short* __restrict__ w1t, unsigned short* __restrict__ w2t,
    unsigned short* __restrict__ woutt)
{
    __shared__ float tile[32][33];
    int bx = blockIdx.x, tid = threadIdx.x;
    const float* src; unsigned short* dst; int Kd, Nd, tr, tc;
    if (bx < 512) {                    // Wq/Wk/Wv/Wo, 2 layers each, 256x256
        int am = bx >> 6, t = bx & 63;
        int m4 = am >> 1, layer = am & 1;
        const float* s4[4] = {Wq, Wk, Wv, Wo};
        src = s4[m4] + (long)layer * 65536;
        if (m4 == 0)      dst = wqkt + (long)layer * 131072;
        else if (m4 == 1) dst = wqkt + (long)layer * 131072 + 65536;
        else if (m4 == 2) dst = wvt + (long)layer * 65536;
        else              dst = wot + (long)layer * 65536;
        Kd = 256; Nd = 256; tr = t >> 3; tc = t & 7;
    } else if (bx < 1024) {            // W1: 2 x (256x1024)
        int idx = bx - 512, mat = idx >> 8, t = idx & 255;
        src = W1 + (long)mat * 262144; dst = w1t + (long)mat * 262144;
        Kd = 256; Nd = 1024; tr = t >> 5; tc = t & 31;
    } else if (bx < 1536) {            // W2: 2 x (1024x256)
        int idx = bx - 1024, mat = idx >> 8, t = idx & 255;
        src = W2 + (long)mat * 262144; dst = w2t + (long)mat * 262144;
        Kd = 1024; Nd = 256; tr = t >> 3; tc = t & 7;
    } else {                           // Wout: 256x512
        int t = bx - 1536;
        src = Wout; dst = woutt; Kd = 256; Nd = 512; tr = t >> 4; tc = t & 15;
    }
    int kr = tid >> 3, nc4 = (tid & 7) * 4;
    float4_t v = *(const float4_t*)&src[(long)(tr * 32 + kr) * Nd + tc * 32 + nc4];
    for (int j = 0; j < 4; ++j) tile[kr][nc4 + j] = v[j];
    __syncthreads();
    int nr = tid >> 3, kc4 = (tid & 7) * 4;
    unsigned short tmp[4];
    for (int j = 0; j < 4; ++j) tmp[j] = f2bf_bits(tile[kc4 + j][nr]);
    uint2 uu;
    uu.x = (unsigned)tmp[0] | ((unsigned)tmp[1] << 16);
    uu.y = (unsigned)tmp[2] | ((unsigned)tmp[3] << 16);
    *(uint2*)&dst[(long)(tc * 32 + nr) * Kd + tr * 32 + kc4] = uu;
}

// ---------------------------------------------------------------------------
// Token embedding gather + rank-2 delta projection
// ---------------------------------------------------------------------------
__global__ __launch_bounds__(256) void embed_kernel(
    const int* __restrict__ tokens, const float* __restrict__ emb,
    const float* __restrict__ w_in, const float* __restrict__ w_out,
    float* __restrict__ x, float* __restrict__ delta)
{
    int bt = blockIdx.x;
    int d  = threadIdx.x;
    int tok = tokens[bt];
    float e = emb[tok * D_ + d];
    x[(long)bt * D_ + d] = e;

    __shared__ float r0s[256], r1s[256];
    r0s[d] = e * w_in[d * 2 + 0];
    r1s[d] = e * w_in[d * 2 + 1];
    __syncthreads();
    for (int off = 128; off > 0; off >>= 1) {
        if (d < off) { r0s[d] += r0s[d + off]; r1s[d] += r1s[d + off]; }
        __syncthreads();
    }
    float r0 = r0s[0], r1 = r1s[0];
    if (d < H_ * NB_) {
        delta[(long)bt * (H_ * NB_) + d] =
            r0 * w_out[d] + r1 * w_out[H_ * NB_ + d];
    }
}

// ---------------------------------------------------------------------------
// cumsum over T per (b, channel) + cos/sin
// ---------------------------------------------------------------------------
__global__ __launch_bounds__(256) void cumsum_kernel(
    const float* __restrict__ delta, const float* __restrict__ omega,
    float* __restrict__ cosb, float* __restrict__ sinb)
{
    int c = blockIdx.x & (H_ * NB_ - 1);
    int b = blockIdx.x >> 7;
    int tid = threadIdx.x;
    float om = omega[c];
    int h = c >> 5, nb = c & (NB_ - 1);

    float vals[8];
    float s = 0.0f;
    for (int i = 0; i < 8; ++i) {
        int t = tid * 8 + i;
        vals[i] = delta[((long)b * T_ + t) * (H_ * NB_) + c];
        s += vals[i];
    }
    __shared__ float sc[256];
    sc[tid] = s;
    __syncthreads();
    for (int off = 1; off < 256; off <<= 1) {
        float v = (tid >= off) ? sc[tid - off] : 0.0f;
        __syncthreads();
        sc[tid] += v;
        __syncthreads();
    }
    float run = sc[tid] - s;
    for (int i = 0; i < 8; ++i) {
        run += vals[i];
        float ang = run * om;
        int t = tid * 8 + i;
        long oi = ((long)(b * H_ + h) * T_ + t) * NB_ + nb;
        cosb[oi] = cosf(ang);
        sinb[oi] = sinf(ang);
    }
}

// ---------------------------------------------------------------------------
// LayerNorm (fp32 in) -> bf16 out. Wave-per-row, no LDS, no barriers.
// ---------------------------------------------------------------------------
__global__ __launch_bounds__(256) void ln_kernel(
    const float* __restrict__ x, const float* __restrict__ g,
    const float* __restrict__ b, unsigned short* __restrict__ out)
{
    int w = threadIdx.x >> 6, lane = threadIdx.x & 63;
    long row = (long)blockIdx.x * 4 + w;
    float4_t v = *(const float4_t*)&x[row * D_ + lane * 4];
    float s = v[0] + v[1] + v[2] + v[3];
    float q = v[0]*v[0] + v[1]*v[1] + v[2]*v[2] + v[3]*v[3];
    for (int off = 1; off < 64; off <<= 1) {
        s += __shfl_xor(s, off);
        q += __shfl_xor(q, off);
    }
    float mu  = s * (1.0f / D_);
    float var = q * (1.0f / D_) - mu * mu;
    float inv = rsqrtf(var + 1e-5f);
    float4_t gg = *(const float4_t*)&g[lane * 4];
    float4_t bb = *(const float4_t*)&b[lane * 4];
    unsigned short h0 = f2bf_bits((v[0] - mu) * inv * gg[0] + bb[0]);
    unsigned short h1 = f2bf_bits((v[1] - mu) * inv * gg[1] + bb[1]);
    unsigned short h2 = f2bf_bits((v[2] - mu) * inv * gg[2] + bb[2]);
    unsigned short h3 = f2bf_bits((v[3] - mu) * inv * gg[3] + bb[3]);
    uint2 uu;
    uu.x = (unsigned)h0 | ((unsigned)h1 << 16);
    uu.y = (unsigned)h2 | ((unsigned)h3 << 16);
    *(uint2*)&out[row * D_ + lane * 4] = uu;
}

// ---------------------------------------------------------------------------
// MFMA GEMM v5: r9's proven v4 engine (BM=BN=BK=64, double-buffered LDS,
// single-tile register prefetch) + XCD-aware grid orientation.
// rowx=1: blockIdx.x = ROW tile, blockIdx.y = COL tile. Linear block id
// = rx + gridDim.x*cy, so id%8 = rx%8 -> all col-blocks sharing one A
// row-panel land on the SAME XCD -> A-panel fetched once per XCD L2
// (was: once per col-block). rowx=0 keeps B-operand locality (for V^T,
// whose large operand is B). Accumulation order unchanged -> bit-identical.
// mode 0: fp32 out, bias per col, optional res add
// mode 1: bf16 out, bias per col, optional gelu
// mode 2: bf16 out, bias per ROW (V^T via swapped operands)
// mode 3: fused Q+K rope epilogue (cols 0-255 = Q with 1/8 scale, 256-511 = K)
// ---------------------------------------------------------------------------
__global__ __launch_bounds__(256) void gemm_mfma(
    const unsigned short* __restrict__ A, const unsigned short* __restrict__ Bt,
    const float* __restrict__ bias, const float* __restrict__ bias2,
    const float* __restrict__ res,
    float* __restrict__ outf, unsigned short* __restrict__ outb,
    const float* __restrict__ ropeC, const float* __restrict__ ropeS,
    int M, int N, int K, int mode, int do_gelu, int rowx)
{
    __shared__ __align__(16) short As[2][64 * 72];
    __shared__ __align__(16) short Bs[2][64 * 72];
    int tid = threadIdx.x;
    int w = tid >> 6, lane = tid & 63, quad = lane >> 4, l16 = lane & 15;
    int n0, r0;
    if (rowx) { r0 = blockIdx.x * 64; n0 = blockIdx.y * 64; }
    else      { n0 = blockIdx.x * 64; r0 = blockIdx.y * 64; }

    float4_t acc[4];
    for (int nt = 0; nt < 4; ++nt) acc[nt] = (float4_t){0.f, 0.f, 0.f, 0.f};

    // stage tile 0 into buffer 0 (transient regs)
    for (int i = 0; i < 2; ++i) {
        int e = tid + 256 * i, row = e >> 3, c8 = e & 7;
        *(short8_t*)&As[0][row * 72 + c8 * 8] =
            *(const short8_t*)&A[(long)(r0 + row) * K + c8 * 8];
        *(short8_t*)&Bs[0][row * 72 + c8 * 8] =
            *(const short8_t*)&Bt[(long)(n0 + row) * K + c8 * 8];
    }
    __syncthreads();

    int cur = 0;
    for (int k0 = 0; k0 < K; k0 += 64) {
        bool have = (k0 + 64 < K);
        // prefetch tile k+1 into registers (in flight during MFMAs below)
        short8_t pA[2], pB[2];
        if (have) {
            for (int i = 0; i < 2; ++i) {
                int e = tid + 256 * i, row = e >> 3, c8 = e & 7;
                pA[i] = *(const short8_t*)&A[(long)(r0 + row) * K + k0 + 64 + c8 * 8];
                pB[i] = *(const short8_t*)&Bt[(long)(n0 + row) * K + k0 + 64 + c8 * 8];
            }
        }
        // compute tile k from LDS[cur]
        for (int kq = 0; kq < 2; ++kq) {
            short8_t a = *(const short8_t*)&As[cur][(w * 16 + l16) * 72 + kq * 32 + quad * 8];
            for (int nt = 0; nt < 4; ++nt) {
                short8_t bfr = *(const short8_t*)&Bs[cur][(nt * 16 + l16) * 72 + kq * 32 + quad * 8];
                acc[nt] = MFMA16(a, bfr, acc[nt]);
            }
        }
        if (have) {
            __syncthreads();     // prior-iteration readers of LDS[cur^1] done
            for (int i = 0; i < 2; ++i) {
                int e = tid + 256 * i, row = e >> 3, c8 = e & 7;
                *(short8_t*)&As[cur ^ 1][row * 72 + c8 * 8] = pA[i];
                *(short8_t*)&Bs[cur ^ 1][row * 72 + c8 * 8] = pB[i];
            }
            __syncthreads();     // next tile visible to all waves
            cur ^= 1;
        }
    }

    for (int nt = 0; nt < 4; ++nt) {
        int n = n0 + nt * 16 + l16;
        for (int r = 0; r < 4; ++r) {
            int row = r0 + w * 16 + quad * 4 + r;
            float v = acc[nt][r];
            if (mode == 2)      v += bias[row];
            else if (mode == 3) v += (n < 256) ? bias[n] : bias2[n - 256];
            else                v += bias[n];
            if (res) v += res[(long)row * N + n];
            if (do_gelu) v = 0.5f * v * (1.0f + erff(v * 0.70710678118654752f));
            if (mode == 0) {
                outf[(long)row * N + n] = v;
            } else if (mode <= 2) {
                outb[(long)row * N + n] = f2bf_bits(v);
            } else {   // mode 3: rope (pairs adjacent cols -> lane^1)
                float vp = __shfl_xor(v, 1);
                bool isK = (n >= 256);
                int nn = isK ? n - 256 : n;
                int bb = row >> 11, t = row & (T_ - 1);
                int hh = nn >> 6, nb = (nn & 63) >> 1;
                long ci = ((long)(bb * H_ + hh) * T_ + t) * NB_ + nb;
                float c = ropeC[ci], sn = ropeS[ci];
                float ov = (l16 & 1) ? (vp * sn + v * c) : (v * c - vp * sn);
                float qs = isK ? 1.0f : 0.125f;
                long off = isK ? (long)B_ * T_ * D_ : 0;
                outb[off + ((long)(bb * H_ + hh) * T_ + t) * DH_ + (nn & 63)] =
                    f2bf_bits(ov * qs);
            }
        }
    }
}

// ---------------------------------------------------------------------------
// MFMA flash attention v6.1: LDS-SHARED K/V tiles (r6 winner) + wave-uniform
// causal-mask branch (mask VALU only on the 1 diagonal lap of 17).
// ---------------------------------------------------------------------------
__global__ __launch_bounds__(512) void attn_mfma(
    const unsigned short* __restrict__ Qb, const unsigned short* __restrict__ Kb,
    const unsigned short* __restrict__ Vt, unsigned short* __restrict__ O)
{
    __shared__ __align__(16) short KsS[2][64 * 72];
    __shared__ __align__(16) short VsS[2][64 * 72];
    union PsOm { short Ps[8][16 * 72]; float Om[4][16 * 66]; };
    __shared__ __align__(16) PsOm U;
    __shared__ float Ml[4][16][2];

    int tid = threadIdx.x;
    int w = tid >> 6, lane = tid & 63;
    int quad = lane >> 4, l16 = lane & 15;
    int bh = blockIdx.x & 15;
    int p  = blockIdx.x >> 4;            // 0..15
    int wr = w & 3;
    int g  = w >> 2;                     // 0 = group A, 1 = group B
    int b = bh >> 2, h = bh & 3;
    int qtS = 31 - p;                    // shared tile

    const unsigned short* kgb = Kb + (long)bh * T_ * DH_;
    const unsigned short* vgb = Vt + (long)h * DH_ * (B_ * T_) + (long)b * T_;
    short* PsW = &U.Ps[w][0];

    int row0 = wr * 16 + (lane >> 3);    // staging row (this lane, i=0)
    int c80  = (lane & 7) * 8;           // staging col offset (shorts)

    // initial Q frags
    int q0 = (g == 0 ? p : qtS) * 64;
    int qglob = q0 + wr * 16 + l16;
    const unsigned short* qp =
        Qb + ((long)bh * T_ + q0 + wr * 16 + l16) * DH_ + quad * 8;
    short8_t aq[2];
    aq[0] = *(const short8_t*)qp;
    aq[1] = *(const short8_t*)(qp + 32);

    float m_r = -3.0e38f, l_r = 0.0f;
    float4_t o[4];
    for (int nt = 0; nt < 4; ++nt) o[nt] = (float4_t){0.f, 0.f, 0.f, 0.f};

    // prologue: stage lap-0 tiles
    {
        int k0n = (g == 0) ? 0 : (16 - p) * 64;
        for (int i = 0; i < 2; ++i) {
            int row = row0 + 8 * i;
            short8_t kv = *(const short8_t*)&kgb[(long)(k0n + row) * DH_ + c80];
            short8_t vv = *(const short8_t*)&vgb[(long)row * (B_ * T_) + k0n + c80];
            *(short8_t*)&KsS[g][row * 72 + c80] = kv;
            *(short8_t*)&VsS[g][row * 72 + c80] = vv;
        }
    }
    __syncthreads();

    for (int j = 0; j < 17; ++j) {
        bool idle  = (g == 1) && (j == 16);
        bool haveN = (j < 16) && !((g == 1) && (j == 15));

        // issue next-lap global loads into registers (latency hides under compute)
        short8_t stK[2], stV[2];
        if (haveN) {
            int jn = j + 1;
            int k0n = (g == 0) ? ((jn <= p) ? jn * 64 : (jn - p - 1) * 64)
                               : (16 - p + jn) * 64;
            for (int i = 0; i < 2; ++i) {
                int row = row0 + 8 * i;
                stK[i] = *(const short8_t*)&kgb[(long)(k0n + row) * DH_ + c80];
                stV[i] = *(const short8_t*)&vgb[(long)row * (B_ * T_) + k0n + c80];
            }
        }

        if (!idle) {
            int k0 = (g == 0) ? ((j <= p) ? j * 64 : (j - p - 1) * 64)
                              : (16 - p + j) * 64;
            bool msk = (g == 0) ? (j == p) : (j == 15);

            // fragments from shared LDS tiles
            short8_t kf[4][2], vb[4][2];
            for (int nt = 0; nt < 4; ++nt) {
                const short* kb_ = &KsS[g][(nt * 16 + l16) * 72 + quad * 8];
                const short* vb_ = &VsS[g][(nt * 16 + l16) * 72 + quad * 8];
                kf[nt][0] = *(const short8_t*)kb_;
                kf[nt][1] = *(const short8_t*)(kb_ + 32);
                vb[nt][0] = *(const short8_t*)vb_;
                vb[nt][1] = *(const short8_t*)(vb_ + 32);
            }

            // S^T = K Q^T: lane holds S[k = nt*16+quad*4+r][q = l16]
            float4_t st[4];
            for (int nt = 0; nt < 4; ++nt) {
                float4_t sa = (float4_t){0.f, 0.f, 0.f, 0.f};
                sa = MFMA16(kf[nt][0], aq[0], sa);
                sa = MFMA16(kf[nt][1], aq[1], sa);
                st[nt] = sa;
            }

            // causal mask: wave-uniform branch (only the diagonal lap pays it)
            float mt = -3.0e38f;
            if (msk) {
                for (int nt = 0; nt < 4; ++nt) {
                    for (int r = 0; r < 4; ++r) {
                        float sv = st[nt][r];
                        if ((k0 + nt * 16 + quad * 4 + r) > qglob) sv = -3.0e38f;
                        st[nt][r] = sv;
                        mt = fmaxf(mt, sv);
                    }
                }
            } else {
                for (int nt = 0; nt < 4; ++nt)
                    for (int r = 0; r < 4; ++r)
                        mt = fmaxf(mt, st[nt][r]);
            }
            mt = fmaxf(mt, __shfl_xor(mt, 16));
            mt = fmaxf(mt, __shfl_xor(mt, 32));

            float mn = fmaxf(m_r, mt);
            float alpha = __expf(m_r - mn);
            m_r = mn;

            float ac[4];
            for (int r = 0; r < 4; ++r) ac[r] = __shfl(alpha, quad * 4 + r);

            float lt = 0.0f;
            for (int nt = 0; nt < 4; ++nt) {
                for (int r = 0; r < 4; ++r) {
                    float pv = __expf(st[nt][r] - m_r);
                    lt += pv;
                    PsW[l16 * 72 + nt * 16 + quad * 4 + r] = (short)f2bf_bits(pv);
                }
            }
            lt += __shfl_xor(lt, 16);
            lt += __shfl_xor(lt, 32);
            l_r = l_r * alpha + lt;

            for (int nt = 0; nt < 4; ++nt)
                for (int r = 0; r < 4; ++r) o[nt][r] *= ac[r];

            // O += P @ V (wave-private P strip)
            for (int kq = 0; kq < 2; ++kq) {
                short8_t pa = *(const short8_t*)&PsW[l16 * 72 + kq * 32 + quad * 8];
                for (int nt = 0; nt < 4; ++nt)
                    o[nt] = MFMA16(pa, vb[nt][kq], o[nt]);
            }

            // A-group transition: finalize tile p, switch to shared tile
            if (g == 0 && j == p) {
                float linv[4];
                for (int r = 0; r < 4; ++r) linv[r] = __shfl(l_r, quad * 4 + r);
                for (int r = 0; r < 4; ++r) {
                    float inv = 1.0f / linv[r];
                    int trow = p * 64 + wr * 16 + quad * 4 + r;
                    long orow = ((long)b * T_ + trow) * D_ + h * 64;
                    for (int nt = 0; nt < 4; ++nt)
                        O[orow + nt * 16 + l16] = f2bf_bits(o[nt][r] * inv);
                }
                m_r = -3.0e38f; l_r = 0.0f;
                for (int nt = 0; nt < 4; ++nt) o[nt] = (float4_t){0.f, 0.f, 0.f, 0.f};
                const unsigned short* qp2 =
                    Qb + ((long)bh * T_ + qtS * 64 + wr * 16 + l16) * DH_ + quad * 8;
                aq[0] = *(const short8_t*)qp2;
                aq[1] = *(const short8_t*)(qp2 + 32);
                qglob = qtS * 64 + wr * 16 + l16;   // unused (no mask in seg 2)
            }
        }

        if (j < 16) {
            __syncthreads();                 // all reads of current tiles done
            if (haveN) {
                for (int i = 0; i < 2; ++i) {
                    int row = row0 + 8 * i;
                    *(short8_t*)&KsS[g][row * 72 + c80] = stK[i];
                    *(short8_t*)&VsS[g][row * 72 + c80] = stV[i];
                }
            }
            __syncthreads();                 // next tiles visible
        }
    }

    __syncthreads();                         // lap-16 Ps reads done before stash
    if (g == 0) {
        for (int nt = 0; nt < 4; ++nt)
            for (int r = 0; r < 4; ++r)
                U.Om[wr][(quad * 4 + r) * 66 + nt * 16 + l16] = o[nt][r];
        if (quad == 0) { Ml[wr][l16][0] = m_r; Ml[wr][l16][1] = l_r; }
    }
    __syncthreads();
    if (g == 1) {
        int q0s = qtS * 64;
        for (int r = 0; r < 4; ++r) {
            int row = quad * 4 + r;
            float mA = Ml[wr][row][0], lA = Ml[wr][row][1];
            float mB = __shfl(m_r, row);
            float lB = __shfl(l_r, row);
            float M  = fmaxf(mA, mB);
            float eA = __expf(mA - M), eB = __expf(mB - M);
            float inv = 1.0f / (lA * eA + lB * eB);
            int trow = q0s + wr * 16 + row;
            long orow = ((long)b * T_ + trow) * D_ + h * 64;
            for (int nt = 0; nt < 4; ++nt) {
                float vm = U.Om[wr][row * 66 + nt * 16 + l16] * eA + o[nt][r] * eB;
                O[orow + nt * 16 + l16] = f2bf_bits(vm * inv);
            }
        }
    }
}

// ---------------------------------------------------------------------------
extern "C" void kernel_launch(void* const* d_in, const int* in_sizes, int n_in,
                              void* d_out, int out_size, void* d_ws, size_t ws_size,
                              hipStream_t stream)
{
    const int*   tokens    = (const int*)d_in[0];
    const float* token_emb = (const float*)d_in[1];
    const float* w_in      = (const float*)d_in[2];
    const float* w_out     = (const float*)d_in[3];
    const float* omega     = (const float*)d_in[4];
    const float* Wq        = (const float*)d_in[5];
    const float* bq        = (const float*)d_in[6];
    const float* Wk        = (const float*)d_in[7];
    const float* bk        = (const float*)d_in[8];
    const float* Wv        = (const float*)d_in[9];
    const float* bv        = (const float*)d_in[10];
    const float* Wo        = (const float*)d_in[11];
    const float* bo        = (const float*)d_in[12];
    const float* ln1_g     = (const float*)d_in[13];
    const float* ln1_b     = (const float*)d_in[14];
    const float* ln2_g     = (const float*)d_in[15];
    const float* ln2_b     = (const float*)d_in[16];
    const float* W1        = (const float*)d_in[17];
    const float* b1        = (const float*)d_in[18];
    const float* W2        = (const float*)d_in[19];
    const float* b2        = (const float*)d_in[20];
    const float* out_g     = (const float*)d_in[21];
    const float* out_b     = (const float*)d_in[22];
    const float* Wout      = (const float*)d_in[23];
    const float* bout      = (const float*)d_in[24];

    const long NTOK = (long)B_ * T_;  // 8192
    float* xbuf = (float*)d_ws;                       // fp32 residual stream 8MB
    float* cosb = xbuf + NTOK * D_;                   // (B,H,T,NB) fp32 4MB
    float* sinb = cosb + NTOK * H_ * NB_;             // 4MB
    float* dbuf = sinb + NTOK * H_ * NB_;             // (B,T,H*NB) fp32 4MB
    unsigned short* hbuf  = (unsigned short*)(dbuf + NTOK * H_ * NB_); // bf16 LN out 4MB
    unsigned short* obuf  = hbuf + NTOK * D_;         // bf16 attn out 4MB
    unsigned short* ffbuf = obuf + NTOK * D_;         // bf16 FFN mid 16MB
    unsigned short* qb16  = ffbuf + NTOK * DFF_;      // bf16 Q (B,H,T,DH) 4MB
    unsigned short* kb16  = qb16 + NTOK * D_;         // bf16 K (B,H,T,DH) 4MB (MUST follow qb16)
    unsigned short* vtb   = kb16 + NTOK * D_;         // bf16 V^T [H*DH][B*T] 4MB
    unsigned short* wqkt  = vtb + NTOK * D_;          // fused Q|K weights 2x131072
    unsigned short* wvt   = wqkt + 2 * 131072;
    unsigned short* wot   = wvt + 2 * 65536;
    unsigned short* w1t   = wot + 2 * 65536;
    unsigned short* w2t   = w1t + 2 * 262144;
    unsigned short* woutt = w2t + 2 * 262144;
    // total ~60 MB

    wt_kernel<<<1664, 256, 0, stream>>>(Wq, Wk, Wv, Wo, W1, W2, Wout,
                                        wqkt, wvt, wot, w1t, w2t, woutt);
    embed_kernel<<<NTOK, 256, 0, stream>>>(tokens, token_emb, w_in, w_out, xbuf, dbuf);
    cumsum_kernel<<<B_ * H_ * NB_, 256, 0, stream>>>(dbuf, omega, cosb, sinb);

    for (int l = 0; l < NL_; ++l) {
        ln_kernel<<<2048, 256, 0, stream>>>(xbuf, ln1_g + l * D_, ln1_b + l * D_, hbuf);
        // fused Q+K: rope + per-half scale/bias (rows in blockIdx.x -> A XCD-local)
        gemm_mfma<<<dim3(128, 8), 256, 0, stream>>>(
            hbuf, wqkt + (long)l * 131072, bq + l * D_, bk + l * D_, nullptr,
            nullptr, qb16, cosb, sinb, (int)NTOK, 512, 256, 3, 0, 1);
        // V^T via swapped operands (large operand is B=hbuf, already XCD-local)
        gemm_mfma<<<dim3(128, 4), 256, 0, stream>>>(
            wvt + (long)l * 65536, hbuf, bv + l * D_, nullptr, nullptr,
            nullptr, vtb, nullptr, nullptr, 256, (int)NTOK, 256, 2, 0, 0);
        attn_mfma<<<256, 512, 0, stream>>>(qb16, kb16, vtb, obuf);
        gemm_mfma<<<dim3(128, 4), 256, 0, stream>>>(
            obuf, wot + (long)l * 65536, bo + l * D_, nullptr, xbuf,
            xbuf, nullptr, nullptr, nullptr, (int)NTOK, 256, 256, 0, 0, 1);
        ln_kernel<<<2048, 256, 0, stream>>>(xbuf, ln2_g + l * D_, ln2_b + l * D_, hbuf);
        gemm_mfma<<<dim3(128, 16), 256, 0, stream>>>(
            hbuf, w1t + (long)l * 262144, b1 + l * DFF_, nullptr, nullptr,
            nullptr, ffbuf, nullptr, nullptr, (int)NTOK, DFF_, 256, 1, 1, 1);
        gemm_mfma<<<dim3(128, 4), 256, 0, stream>>>(
            ffbuf, w2t + (long)l * 262144, b2 + l * D_, nullptr, xbuf,
            xbuf, nullptr, nullptr, nullptr, (int)NTOK, 256, 1024, 0, 0, 1);
    }

    ln_kernel<<<2048, 256, 0, stream>>>(xbuf, out_g, out_b, hbuf);
    gemm_mfma<<<dim3(128, 8), 256, 0, stream>>>(
        hbuf, woutt, bout, nullptr, nullptr,
        (float*)d_out, nullptr, nullptr, nullptr, (int)NTOK, V_, 256, 0, 0, 1);
}